// Round 20
// baseline (305.634 us; speedup 1.0000x reference)
//
#include <hip/hip_runtime.h>

#define DEVI __device__ __forceinline__

typedef __attribute__((ext_vector_type(8))) short short8;
typedef __attribute__((ext_vector_type(4))) float f32x4;

static constexpr int NN = 8192;
static constexpr int DD = 512;
static constexpr unsigned LOB = 0x3EFE0000u;  // bits(0.49609375f)
static constexpr unsigned HIB = 0x3F020000u;  // bits(0.5078125f) -> 0x40000 exact-bit bins
static constexpr long long K_RANK = 16775167LL;  // (m-1)/2, m = N(N-1)/2

// ws layout (bytes)
static constexpr size_t WS_HIST   = 0;
static constexpr size_t WS_CNT    = 1048576;
static constexpr size_t WS_MED    = 1048832;
static constexpr size_t WS_COARSE = 1049088;                        // u32 coarse[1024]
static constexpr size_t WS_XB     = 2097152;                        // bf16 X [8192][512]
static constexpr size_t WS_W1B  = WS_XB  + (size_t)NN * DD * 2;     // bf16 W1 [512][512]
static constexpr size_t WS_W2B  = WS_W1B + (size_t)DD * DD * 2;     // bf16 W2 [512][512]
static constexpr size_t WS_FCXT = WS_W2B + (size_t)DD * DD * 2;     // bf16 fcX^T [512][8192]
static constexpr size_t WS_FC2  = WS_FCXT + (size_t)NN * DD * 2;    // f32 fc2X [8192][512]
static constexpr size_t WS_UP   = WS_FC2 + (size_t)NN * DD * 4;     // bf16 U partials [4][8192][512]
static constexpr size_t WS_ZP   = WS_UP  + (size_t)4 * NN * DD * 2; // f32 Z partials [4][8192]

DEVI unsigned short f2bf(float f) {
  unsigned u = __float_as_uint(f);
  u += 0x7fffu + ((u >> 16) & 1u);
  return (unsigned short)(u >> 16);
}
DEVI float bf2f(unsigned short h) { return __uint_as_float(((unsigned)h) << 16); }
DEVI int swz(int row, int kq) { return kq ^ ((row >> 1) & 3); }

DEVI void gl_lds16(const void* g, void* l) {
  __builtin_amdgcn_global_load_lds(
      (const __attribute__((address_space(1))) unsigned*)g,
      (__attribute__((address_space(3))) unsigned*)l, 16, 0, 0);
}

// ================= zero_k: scratch init (owned kernel; no hipMemsetAsync) =============
__global__ __launch_bounds__(256) void zero_k(uint4* __restrict__ hist4,
                                              unsigned* __restrict__ cntmed) {
  hist4[blockIdx.x * 256 + threadIdx.x] = (uint4){0u, 0u, 0u, 0u};
  if (blockIdx.x == 0 && threadIdx.x < 2) cntmed[threadIdx.x * 64] = 0u;
}

// ================= stage1: convert (bx<128) || hist (bx>=128, 896 blocks) =============

DEVI void convert_body(const float* __restrict__ X, const float* __restrict__ W1,
                       const float* __restrict__ W2, unsigned short* __restrict__ Xb,
                       unsigned short* __restrict__ W1b, unsigned short* __restrict__ W2b,
                       int cb, int tid) {
  const long long NX = (long long)NN * DD;   // 4194304
  const long long NW = (long long)DD * DD;   // 262144
  const long long total4 = (NX + 2 * NW) / 4;
  for (long long q = (long long)cb * 512 + tid; q < total4; q += 65536LL) {
    long long e = q << 2;
    const float4* src; unsigned short* dst; long long off;
    if (e < NX)           { src = (const float4*)X;  dst = Xb;  off = e; }
    else if (e < NX + NW) { src = (const float4*)W1; dst = W1b; off = e - NX; }
    else                  { src = (const float4*)W2; dst = W2b; off = e - NX - NW; }
    float4 v = src[off >> 2];
    ushort4 o;
    o.x = f2bf(v.x); o.y = f2bf(v.y); o.z = f2bf(v.z); o.w = f2bf(v.w);
    *(ushort4*)(dst + off) = o;
  }
}

// hist: 8-deep memory-level parallelism (R13/R14-proven body).
DEVI void hist_body(const float* __restrict__ A, unsigned* __restrict__ hist,
                    unsigned* __restrict__ below, int hb, int tid) {
  unsigned cnt = 0;
  const float4* A4 = (const float4*)A;
  const long long STR = 458752LL;  // 896 blocks * 512 threads
#pragma unroll 1
  for (long long q0 = (long long)hb * 512 + tid; q0 < 16777216LL; q0 += 8 * STR) {
    float4 v[8];
    int act = 0;
#pragma unroll
    for (int i = 0; i < 8; ++i) {  // issue up to 8 independent loads
      long long qi = q0 + i * STR;
      if (qi < 16777216LL) {
        int row = (int)(qi >> 11);
        int col = (int)((qi & 2047) << 2);
        if (col + 3 > row) { act |= 1 << i; v[i] = A4[qi]; }
      }
    }
#pragma unroll
    for (int i = 0; i < 8; ++i) {
      if (act & (1 << i)) {
        long long qi = q0 + i * STR;
        int row = (int)(qi >> 11);
        int col = (int)((qi & 2047) << 2);
        float vv[4] = {v[i].x, v[i].y, v[i].z, v[i].w};
#pragma unroll
        for (int j = 0; j < 4; ++j) {
          if (col + j > row) {
            unsigned u = __float_as_uint(vv[j]);
            if (u < LOB) cnt++;
            else if (u < HIB) atomicAdd(&hist[u - LOB], 1u);
          }
        }
      }
    }
  }
  for (int off = 32; off > 0; off >>= 1) cnt += __shfl_down(cnt, off);
  if ((tid & 63) == 0 && cnt) atomicAdd(below, cnt);
}

__global__ __launch_bounds__(512) void stage1_k(const float* __restrict__ A,
                                                const float* __restrict__ X,
                                                const float* __restrict__ W1,
                                                const float* __restrict__ W2,
                                                unsigned* __restrict__ hist,
                                                unsigned* __restrict__ below,
                                                unsigned short* __restrict__ Xb,
                                                unsigned short* __restrict__ W1b,
                                                unsigned short* __restrict__ W2b) {
  const int bx = blockIdx.x;
  if (bx < 128) convert_body(X, W1, W2, Xb, W1b, W2b, bx, threadIdx.x);
  else          hist_body(A, hist, below, bx - 128, threadIdx.x);
}

// ===== stage2: gemm1 (bx<256) || gemm2 (<512) || coarse hist sums (512..1023) =========

// NT-GEMM (bf16 MFMA): out[m,n] = sum_k Am[m,k]*Bm[n,k] + bias. 64x256 tile, BK=32.
template <bool BROW, bool OBF>
DEVI void gemm_small_body(const unsigned short* __restrict__ Am,
                          const unsigned short* __restrict__ Bm,
                          const float* __restrict__ bias, void* __restrict__ outp,
                          int ldout, int m0, int n0, char* apB, char* btB) {
  const int tid = threadIdx.x, lane = tid & 63, w = tid >> 6;
  const int wm = w >> 2, wn = w & 3;
  const int lr = lane & 15, lq = lane >> 4;
  const int rL = lane >> 2, kq = lane & 3;
  f32x4 acc[2][4];
#pragma unroll
  for (int i = 0; i < 2; ++i)
#pragma unroll
    for (int j = 0; j < 4; ++j) acc[i][j] = (f32x4){0.f, 0.f, 0.f, 0.f};

#pragma unroll 1
  for (int kt = 0; kt < 16; ++kt) {
    const int k0 = kt * 32;
    __syncthreads();
    if (w < 4) {
      int r = w * 16 + rL;
      gl_lds16(Am + ((size_t)(m0 + r) * DD + k0 + swz(r, kq) * 8), apB + w * 1024);
    }
#pragma unroll
    for (int i = 0; i < 2; ++i) {
      int blk = w * 2 + i;
      int r = blk * 16 + rL;
      gl_lds16(Bm + ((size_t)(n0 + r) * DD + k0 + swz(r, kq) * 8), btB + blk * 1024);
    }
    __syncthreads();
    short8 a[2], b[4];
#pragma unroll
    for (int fr = 0; fr < 2; ++fr) {
      int r = wm * 32 + fr * 16 + lr;
      a[fr] = *(const short8*)(apB + r * 64 + swz(r, lq) * 16);
    }
#pragma unroll
    for (int fc = 0; fc < 4; ++fc) {
      int r = wn * 64 + fc * 16 + lr;
      b[fc] = *(const short8*)(btB + r * 64 + swz(r, lq) * 16);
    }
#pragma unroll
    for (int fr = 0; fr < 2; ++fr)
#pragma unroll
      for (int fc = 0; fc < 4; ++fc)
        acc[fr][fc] = __builtin_amdgcn_mfma_f32_16x16x32_bf16(a[fr], b[fc], acc[fr][fc], 0, 0, 0);
  }
#pragma unroll
  for (int fr = 0; fr < 2; ++fr)
#pragma unroll
    for (int fc = 0; fc < 4; ++fc)
#pragma unroll
      for (int j = 0; j < 4; ++j) {
        int row = m0 + wm * 32 + fr * 16 + lq * 4 + j;
        int col = n0 + wn * 64 + fc * 16 + lr;
        float v = acc[fr][fc][j] + (BROW ? bias[row] : bias[col]);
        if (OBF) ((unsigned short*)outp)[(size_t)row * ldout + col] = f2bf(v);
        else     ((float*)outp)[(size_t)row * ldout + col] = v;
      }
}

__global__ __launch_bounds__(512, 2) void stage2_k(const unsigned short* __restrict__ Xb,
                                                   const unsigned short* __restrict__ W1b,
                                                   const unsigned short* __restrict__ W2b,
                                                   const float* __restrict__ b1,
                                                   const float* __restrict__ b2,
                                                   unsigned short* __restrict__ fcXT,
                                                   float* __restrict__ fc2,
                                                   const unsigned* __restrict__ hist,
                                                   unsigned* __restrict__ coarse) {
  __shared__ alignas(16) char plds[20480];
  const int bx = blockIdx.x;
  if (bx < 256) {
    // fcXT[o][n] = sum_k W1[o,k]*X[n,k] + b1[o]; bf16 [512][8192]
    int m0 = ((bx >> 3) & 7) * 64;
    int n0 = ((bx & 7) | ((bx >> 6) << 3)) * 256;
    gemm_small_body<true, true>(W1b, Xb, b1, (void*)fcXT, NN, m0, n0, plds, plds + 4096);
  } else if (bx < 512) {
    // fc2[n][o] = sum_k X[n,k]*W2[o,k] + b2[o]; fp32 [8192][512]
    int q = bx - 256;
    gemm_small_body<false, false>(Xb, W2b, b2, (void*)fc2, DD,
                                  (q >> 1) * 64, (q & 1) * 256, plds, plds + 4096);
  } else {
    // coarse: block handles groups {2*(bx-512), 2*(bx-512)+1} via 256-thread halves
    const int tid = threadIdx.x;
    const int half = tid >> 8;                       // 0 or 1
    const int g = ((bx - 512) << 1) | half;
    unsigned v = hist[g * 256 + (tid & 255)];
    for (int off = 32; off > 0; off >>= 1) v += __shfl_down(v, off);
    unsigned* part = (unsigned*)plds;                // 8 wave slots
    if ((tid & 63) == 0) part[tid >> 6] = v;
    __syncthreads();
    if ((tid & 255) == 0)
      coarse[g] = part[half * 4] + part[half * 4 + 1] + part[half * 4 + 2] + part[half * 4 + 3];
  }
}

// ================= median select: coarse scan + owner drill-down =================
__global__ __launch_bounds__(1024) void select_k(const unsigned* __restrict__ hist,
                                                 const unsigned* __restrict__ coarse,
                                                 const unsigned* __restrict__ below,
                                                 unsigned* __restrict__ med) {
  __shared__ unsigned ssum[1024];
  __shared__ int owner;
  __shared__ unsigned tg_s;
  const int t = threadIdx.x;
  unsigned own = coarse[t];
  ssum[t] = own;
  __syncthreads();
  for (int off = 1; off < 1024; off <<= 1) {
    unsigned v = (t >= off) ? ssum[t - off] : 0u;
    __syncthreads();
    ssum[t] += v;
    __syncthreads();
  }
  long long target = K_RANK - (long long)(*below);
  unsigned incl = ssum[t];
  unsigned excl = incl - own;
  if (target >= (long long)excl && target < (long long)incl) {
    owner = t;
    tg_s = (unsigned)(target - (long long)excl);
  }
  __syncthreads();
  const int to = owner;
  const unsigned tg = tg_s;
  unsigned v256 = (t < 256) ? hist[to * 256 + t] : 0u;
  __syncthreads();
  if (t < 256) ssum[t] = v256;
  __syncthreads();
  for (int off = 1; off < 256; off <<= 1) {
    unsigned v = (t < 256 && t >= off) ? ssum[t - off] : 0u;
    __syncthreads();
    if (t < 256) ssum[t] += v;
    __syncthreads();
  }
  if (t < 256) {
    unsigned incl2 = ssum[t];
    unsigned excl2 = incl2 - v256;
    if (tg >= excl2 && tg < incl2) *med = LOB + (unsigned)(to * 256 + t);
  }
}

// ================= main GEMM: 128x512 tile, split-K=4, BK=64 as 2 proven sub-tiles ====
// BK 32->64 halves the barrier count (64->32 iters), amortizing the measured
// ~4000cyc/iter fixed latency exposure. SPILL-PROOF: no inline asm, no hand vmcnt —
// B(k+1) via gl_lds (8/thread), A(k+1) via compiler-tracked C++ loads + CONV8 x2,
// one __syncthreads per iter (legal with dbuf: reads of buf[k&1] precede the barrier,
// writes to buf[k&1] happen after it in iter k+1). Layout = two verbatim R6 sub-tiles
// per buffer (A [2][128][64B], B [2][512][64B], proven swz()). LDS = 2x16K + 2x64K
// = 163840B (full pool; 1 block/CU as before).
static constexpr int LDS_A0 = 0;
static constexpr int LDS_A1 = 16384;
static constexpr int LDS_B0 = 32768;
static constexpr int LDS_B1 = 98304;

__global__ __launch_bounds__(512, 2) void main_gemm_k(const float* __restrict__ A,
                                                      const unsigned short* __restrict__ fcXT,
                                                      const unsigned* __restrict__ medp,
                                                      unsigned short* __restrict__ Up,
                                                      float* __restrict__ Zp) {
  __shared__ alignas(16) char lds[163840];
  const int tid = threadIdx.x, lane = tid & 63, w = tid >> 6;
  const int wm = w >> 2, wn = w & 3;
  const int lr = lane & 15, lq = lane >> 4;
  const int fid = blockIdx.x;
  const int xcd = fid & 7;
  const int ks = xcd >> 1;
  const int m0 = (((xcd & 1) << 5) | (fid >> 3)) << 7;
  const int kbase = ks * 2048;
  const float med = __uint_as_float(*medp);
  const int rB = lane >> 2, kqB = lane & 3;
  const int rA = tid >> 2, cqA = tid & 3;
  const float* aRow = A + (size_t)(m0 + rA) * NN;
  const int ldsAw = rA * 64 + swz(rA, cqA) * 16;

  float zacc = 0.f;
  f32x4 acc[4][8];
#pragma unroll
  for (int i = 0; i < 4; ++i)
#pragma unroll
    for (int j = 0; j < 8; ++j) acc[i][j] = (f32x4){0.f, 0.f, 0.f, 0.f};

#define CONV8(V0, V1, DST)                                                     \
  {                                                                            \
    float vv[8] = {V0.x, V0.y, V0.z, V0.w, V1.x, V1.y, V1.z, V1.w};            \
    short8 pb;                                                                 \
    _Pragma("unroll")                                                          \
    for (int j = 0; j < 8; ++j) {                                              \
      float a_ = vv[j];                                                        \
      float p_ = (a_ < med) ? 1.0f : __expf(a_);                               \
      unsigned short h_ = f2bf(p_);                                            \
      pb[j] = (short)h_;                                                       \
      zacc += bf2f(h_);                                                        \
    }                                                                          \
    *(short8*)(DST) = pb;                                                      \
  }

  // stage 64-col B tile (2 sub-tiles, 8 gl_lds/thread) into buffer at BBASE
#define STAGE_B(KOFF, BBASE)                                                   \
  _Pragma("unroll")                                                            \
  for (int s = 0; s < 2; ++s) {                                                \
    _Pragma("unroll")                                                          \
    for (int i = 0; i < 4; ++i) {                                              \
      int blk = w * 4 + i;                                                     \
      int o = blk * 16 + rB;                                                   \
      gl_lds16(fcXT + ((size_t)o * NN + (KOFF) + s * 32 + swz(o, kqB) * 8),    \
               lds + (BBASE) + s * 32768 + blk * 1024);                        \
    }                                                                          \
  }

  // load + convert 64-col A tile (2 sub-tiles, compiler-tracked loads) into ABASE
#define LOAD_CONV_A(KOFF, ABASE)                                               \
  {                                                                            \
    const float* ap_ = aRow + (KOFF) + cqA * 8;                                \
    float4 t0_ = *(const float4*)ap_;                                          \
    float4 t1_ = *(const float4*)(ap_ + 4);                                    \
    float4 t2_ = *(const float4*)(ap_ + 32);                                   \
    float4 t3_ = *(const float4*)(ap_ + 36);                                   \
    CONV8(t0_, t1_, lds + (ABASE) + ldsAw);                                    \
    CONV8(t2_, t3_, lds + (ABASE) + 8192 + ldsAw);                             \
  }

  // ---- prologue: B(0)->B0, A(0)->A0, barrier ----
  STAGE_B(kbase, LDS_B0);
  LOAD_CONV_A(kbase, LDS_A0);
  __syncthreads();

  // iter kt (32 total): issue B(kt+1)->B[NCUR]; 2 sub-steps of {ds_read, 32 MFMA}
  // on CUR; load+conv A(kt+1)->A[NCUR]; __syncthreads (drains gl_lds + ds_writes).
#define ITER(KT, CUR, NCUR)                                                    \
  {                                                                            \
    const int kt_ = (KT);                                                      \
    if (kt_ < 31) { STAGE_B(kbase + (kt_ + 1) * 64, LDS_B##NCUR); }            \
    _Pragma("unroll")                                                          \
    for (int ksb = 0; ksb < 2; ++ksb) {                                        \
      short8 af[4], bfr[8];                                                    \
      _Pragma("unroll")                                                        \
      for (int fr = 0; fr < 4; ++fr) {                                         \
        int r = wm * 64 + fr * 16 + lr;                                        \
        af[fr] = *(const short8*)(lds + LDS_A##CUR + ksb * 8192 +              \
                                  r * 64 + swz(r, lq) * 16);                   \
      }                                                                        \
      _Pragma("unroll")                                                        \
      for (int fc = 0; fc < 8; ++fc) {                                         \
        int o = wn * 128 + fc * 16 + lr;                                       \
        bfr[fc] = *(const short8*)(lds + LDS_B##CUR + ksb * 32768 +            \
                                   o * 64 + swz(o, lq) * 16);                  \
      }                                                                        \
      __builtin_amdgcn_s_setprio(1);                                           \
      _Pragma("unroll")                                                        \
      for (int fr = 0; fr < 4; ++fr)                                           \
        _Pragma("unroll")                                                      \
        for (int fc = 0; fc < 8; ++fc)                                         \
          acc[fr][fc] = __builtin_amdgcn_mfma_f32_16x16x32_bf16(               \
              af[fr], bfr[fc], acc[fr][fc], 0, 0, 0);                          \
      __builtin_amdgcn_s_setprio(0);                                           \
    }                                                                          \
    if (kt_ < 31) {                                                            \
      LOAD_CONV_A(kbase + (kt_ + 1) * 64, LDS_A##NCUR);                        \
      __syncthreads();                                                         \
    }                                                                          \
  }

#pragma unroll 1
  for (int t2 = 0; t2 < 16; ++t2) {
    ITER(2 * t2,     0, 1);
    ITER(2 * t2 + 1, 1, 0);
  }
#undef ITER
#undef LOAD_CONV_A
#undef STAGE_B
#undef CONV8

  // ---- epilogue: rowsum reduce (4 threads per row), Up writes ----
  zacc += __shfl_xor(zacc, 1);
  zacc += __shfl_xor(zacc, 2);
  if ((lane & 3) == 0) Zp[(size_t)ks * NN + m0 + rA] = zacc;
#pragma unroll
  for (int fr = 0; fr < 4; ++fr)
#pragma unroll
    for (int fc = 0; fc < 8; ++fc)
#pragma unroll
      for (int j = 0; j < 4; ++j) {
        int row = m0 + wm * 64 + fr * 16 + lq * 4 + j;
        int col = wn * 128 + fc * 16 + lr;
        Up[((size_t)ks << 22) + ((size_t)row << 9) + col] = f2bf(acc[fr][fc][j]);
      }
}

// ================= split-K reduce + epilogue =================
__global__ __launch_bounds__(256) void reduce_k(const unsigned short* __restrict__ Up,
                                                const float* __restrict__ Zp,
                                                const float* __restrict__ fc2,
                                                float* __restrict__ out) {
  long long t = (long long)blockIdx.x * blockDim.x + threadIdx.x;
  if (t >= (long long)NN * DD / 8) return;
  long long base = t << 3;
  int row = (int)(base >> 9);
  float Z = Zp[row] + Zp[NN + row] + Zp[2 * NN + row] + Zp[3 * NN + row];
  float inv = 0.9f / Z;
  float s[8] = {0, 0, 0, 0, 0, 0, 0, 0};
#pragma unroll
  for (int sp = 0; sp < 4; ++sp) {
    const uint4 u = *(const uint4*)(Up + ((long long)sp << 22) + base);
    const unsigned uu[4] = {u.x, u.y, u.z, u.w};
#pragma unroll
    for (int j = 0; j < 4; ++j) {
      s[2 * j]     += __uint_as_float(uu[j] << 16);
      s[2 * j + 1] += __uint_as_float(uu[j] & 0xffff0000u);
    }
  }
  float4 fa = *(const float4*)(fc2 + base);
  float4 fb = *(const float4*)(fc2 + base + 4);
  float fv[8] = {fa.x, fa.y, fa.z, fa.w, fb.x, fb.y, fb.z, fb.w};
  float o[8];
#pragma unroll
  for (int j = 0; j < 8; ++j) {
    float v = 0.1f * fv[j] + inv * s[j];
    o[j] = v >= 0.f ? v : 0.01f * v;
  }
  *(float4*)(out + base)     = (float4){o[0], o[1], o[2], o[3]};
  *(float4*)(out + base + 4) = (float4){o[4], o[5], o[6], o[7]};
}

extern "C" void kernel_launch(void* const* d_in, const int* in_sizes, int n_in,
                              void* d_out, int out_size, void* d_ws, size_t ws_size,
                              hipStream_t stream) {
  const float* A  = (const float*)d_in[0];
  const float* X  = (const float*)d_in[1];
  const float* W1 = (const float*)d_in[2];
  const float* b1 = (const float*)d_in[3];
  const float* W2 = (const float*)d_in[4];
  const float* b2 = (const float*)d_in[5];
  char* ws = (char*)d_ws;
  unsigned* hist   = (unsigned*)(ws + WS_HIST);
  unsigned* cnt    = (unsigned*)(ws + WS_CNT);
  unsigned* med    = (unsigned*)(ws + WS_MED);
  unsigned* coarse = (unsigned*)(ws + WS_COARSE);
  unsigned short* Xb   = (unsigned short*)(ws + WS_XB);
  unsigned short* W1b  = (unsigned short*)(ws + WS_W1B);
  unsigned short* W2b  = (unsigned short*)(ws + WS_W2B);
  unsigned short* fcXT = (unsigned short*)(ws + WS_FCXT);
  float* fc2           = (float*)(ws + WS_FC2);
  unsigned short* Upp  = (unsigned short*)(ws + WS_UP);
  float* Zp            = (float*)(ws + WS_ZP);

  hipLaunchKernelGGL(zero_k, dim3(256), dim3(256), 0, stream, (uint4*)hist, cnt);
  hipLaunchKernelGGL(stage1_k, dim3(1024), dim3(512), 0, stream,
                     A, X, W1, W2, hist, cnt, Xb, W1b, W2b);
  hipLaunchKernelGGL(stage2_k, dim3(1024), dim3(512), 0, stream,
                     Xb, W1b, W2b, b1, b2, fcXT, fc2, hist, coarse);
  hipLaunchKernelGGL(select_k, dim3(1), dim3(1024), 0, stream, hist, coarse, cnt, med);
  hipLaunchKernelGGL(main_gemm_k, dim3(256), dim3(512), 0, stream, A, fcXT, med, Upp, Zp);
  hipLaunchKernelGGL(reduce_k, dim3(2048), dim3(256), 0, stream, Upp, Zp, fc2, (float*)d_out);
}

// Round 21
// 296.985 us; speedup vs baseline: 1.0291x; 1.0291x over previous
//
#include <hip/hip_runtime.h>

#define DEVI __device__ __forceinline__

typedef __attribute__((ext_vector_type(8))) short short8;
typedef __attribute__((ext_vector_type(4))) float f32x4;

static constexpr int NN = 8192;
static constexpr int DD = 512;
static constexpr unsigned LOB = 0x3EFE0000u;  // bits(0.49609375f)
static constexpr unsigned HIB = 0x3F020000u;  // bits(0.5078125f) -> 0x40000 exact-bit bins
static constexpr long long K_RANK = 16775167LL;  // (m-1)/2, m = N(N-1)/2

// ws layout (bytes)
static constexpr size_t WS_HIST   = 0;
static constexpr size_t WS_CNT    = 1048576;
static constexpr size_t WS_MED    = 1048832;
static constexpr size_t WS_COARSE = 1049088;                        // u32 coarse[1024]
static constexpr size_t WS_XB     = 2097152;                        // bf16 X [8192][512]
static constexpr size_t WS_W1B  = WS_XB  + (size_t)NN * DD * 2;     // bf16 W1 [512][512]
static constexpr size_t WS_W2B  = WS_W1B + (size_t)DD * DD * 2;     // bf16 W2 [512][512]
static constexpr size_t WS_FCXT = WS_W2B + (size_t)DD * DD * 2;     // bf16 fcX^T [512][8192]
static constexpr size_t WS_FC2  = WS_FCXT + (size_t)NN * DD * 2;    // f32 fc2X [8192][512]
static constexpr size_t WS_UP   = WS_FC2 + (size_t)NN * DD * 4;     // bf16 U partials [4][8192][512]
static constexpr size_t WS_ZP   = WS_UP  + (size_t)4 * NN * DD * 2; // f32 Z partials [4][8192]

DEVI unsigned short f2bf(float f) {
  unsigned u = __float_as_uint(f);
  u += 0x7fffu + ((u >> 16) & 1u);
  return (unsigned short)(u >> 16);
}
DEVI float bf2f(unsigned short h) { return __uint_as_float(((unsigned)h) << 16); }
DEVI int swz(int row, int kq) { return kq ^ ((row >> 1) & 3); }

DEVI void gl_lds16(const void* g, void* l) {
  __builtin_amdgcn_global_load_lds(
      (const __attribute__((address_space(1))) unsigned*)g,
      (__attribute__((address_space(3))) unsigned*)l, 16, 0, 0);
}

#define VMCNT(n) asm volatile("s_waitcnt vmcnt(" #n ")" ::: "memory")
#define LGKM0 asm volatile("s_waitcnt lgkmcnt(0)" ::: "memory")

// ================= zero_k: scratch init (owned kernel; no hipMemsetAsync) =============
__global__ __launch_bounds__(256) void zero_k(uint4* __restrict__ hist4,
                                              unsigned* __restrict__ cntmed) {
  hist4[blockIdx.x * 256 + threadIdx.x] = (uint4){0u, 0u, 0u, 0u};
  if (blockIdx.x == 0 && threadIdx.x < 2) cntmed[threadIdx.x * 64] = 0u;
}

// ================= stage1: convert (bx<128) || hist (bx>=128, 896 blocks) =============

DEVI void convert_body(const float* __restrict__ X, const float* __restrict__ W1,
                       const float* __restrict__ W2, unsigned short* __restrict__ Xb,
                       unsigned short* __restrict__ W1b, unsigned short* __restrict__ W2b,
                       int cb, int tid) {
  const long long NX = (long long)NN * DD;   // 4194304
  const long long NW = (long long)DD * DD;   // 262144
  const long long total4 = (NX + 2 * NW) / 4;
  for (long long q = (long long)cb * 512 + tid; q < total4; q += 65536LL) {
    long long e = q << 2;
    const float4* src; unsigned short* dst; long long off;
    if (e < NX)           { src = (const float4*)X;  dst = Xb;  off = e; }
    else if (e < NX + NW) { src = (const float4*)W1; dst = W1b; off = e - NX; }
    else                  { src = (const float4*)W2; dst = W2b; off = e - NX - NW; }
    float4 v = src[off >> 2];
    ushort4 o;
    o.x = f2bf(v.x); o.y = f2bf(v.y); o.z = f2bf(v.z); o.w = f2bf(v.w);
    *(ushort4*)(dst + off) = o;
  }
}

// hist: 8-deep memory-level parallelism (R13/R14-proven body).
DEVI void hist_body(const float* __restrict__ A, unsigned* __restrict__ hist,
                    unsigned* __restrict__ below, int hb, int tid) {
  unsigned cnt = 0;
  const float4* A4 = (const float4*)A;
  const long long STR = 458752LL;  // 896 blocks * 512 threads
#pragma unroll 1
  for (long long q0 = (long long)hb * 512 + tid; q0 < 16777216LL; q0 += 8 * STR) {
    float4 v[8];
    int act = 0;
#pragma unroll
    for (int i = 0; i < 8; ++i) {  // issue up to 8 independent loads
      long long qi = q0 + i * STR;
      if (qi < 16777216LL) {
        int row = (int)(qi >> 11);
        int col = (int)((qi & 2047) << 2);
        if (col + 3 > row) { act |= 1 << i; v[i] = A4[qi]; }
      }
    }
#pragma unroll
    for (int i = 0; i < 8; ++i) {
      if (act & (1 << i)) {
        long long qi = q0 + i * STR;
        int row = (int)(qi >> 11);
        int col = (int)((qi & 2047) << 2);
        float vv[4] = {v[i].x, v[i].y, v[i].z, v[i].w};
#pragma unroll
        for (int j = 0; j < 4; ++j) {
          if (col + j > row) {
            unsigned u = __float_as_uint(vv[j]);
            if (u < LOB) cnt++;
            else if (u < HIB) atomicAdd(&hist[u - LOB], 1u);
          }
        }
      }
    }
  }
  for (int off = 32; off > 0; off >>= 1) cnt += __shfl_down(cnt, off);
  if ((tid & 63) == 0 && cnt) atomicAdd(below, cnt);
}

__global__ __launch_bounds__(512) void stage1_k(const float* __restrict__ A,
                                                const float* __restrict__ X,
                                                const float* __restrict__ W1,
                                                const float* __restrict__ W2,
                                                unsigned* __restrict__ hist,
                                                unsigned* __restrict__ below,
                                                unsigned short* __restrict__ Xb,
                                                unsigned short* __restrict__ W1b,
                                                unsigned short* __restrict__ W2b) {
  const int bx = blockIdx.x;
  if (bx < 128) convert_body(X, W1, W2, Xb, W1b, W2b, bx, threadIdx.x);
  else          hist_body(A, hist, below, bx - 128, threadIdx.x);
}

// ===== stage2: gemm1 (bx<256) || gemm2 (<512) || coarse hist sums (512..1023) =========

// NT-GEMM (bf16 MFMA): out[m,n] = sum_k Am[m,k]*Bm[n,k] + bias. 64x256 tile, BK=32.
template <bool BROW, bool OBF>
DEVI void gemm_small_body(const unsigned short* __restrict__ Am,
                          const unsigned short* __restrict__ Bm,
                          const float* __restrict__ bias, void* __restrict__ outp,
                          int ldout, int m0, int n0, char* apB, char* btB) {
  const int tid = threadIdx.x, lane = tid & 63, w = tid >> 6;
  const int wm = w >> 2, wn = w & 3;
  const int lr = lane & 15, lq = lane >> 4;
  const int rL = lane >> 2, kq = lane & 3;
  f32x4 acc[2][4];
#pragma unroll
  for (int i = 0; i < 2; ++i)
#pragma unroll
    for (int j = 0; j < 4; ++j) acc[i][j] = (f32x4){0.f, 0.f, 0.f, 0.f};

#pragma unroll 1
  for (int kt = 0; kt < 16; ++kt) {
    const int k0 = kt * 32;
    __syncthreads();
    if (w < 4) {
      int r = w * 16 + rL;
      gl_lds16(Am + ((size_t)(m0 + r) * DD + k0 + swz(r, kq) * 8), apB + w * 1024);
    }
#pragma unroll
    for (int i = 0; i < 2; ++i) {
      int blk = w * 2 + i;
      int r = blk * 16 + rL;
      gl_lds16(Bm + ((size_t)(n0 + r) * DD + k0 + swz(r, kq) * 8), btB + blk * 1024);
    }
    __syncthreads();
    short8 a[2], b[4];
#pragma unroll
    for (int fr = 0; fr < 2; ++fr) {
      int r = wm * 32 + fr * 16 + lr;
      a[fr] = *(const short8*)(apB + r * 64 + swz(r, lq) * 16);
    }
#pragma unroll
    for (int fc = 0; fc < 4; ++fc) {
      int r = wn * 64 + fc * 16 + lr;
      b[fc] = *(const short8*)(btB + r * 64 + swz(r, lq) * 16);
    }
#pragma unroll
    for (int fr = 0; fr < 2; ++fr)
#pragma unroll
      for (int fc = 0; fc < 4; ++fc)
        acc[fr][fc] = __builtin_amdgcn_mfma_f32_16x16x32_bf16(a[fr], b[fc], acc[fr][fc], 0, 0, 0);
  }
#pragma unroll
  for (int fr = 0; fr < 2; ++fr)
#pragma unroll
    for (int fc = 0; fc < 4; ++fc)
#pragma unroll
      for (int j = 0; j < 4; ++j) {
        int row = m0 + wm * 32 + fr * 16 + lq * 4 + j;
        int col = n0 + wn * 64 + fc * 16 + lr;
        float v = acc[fr][fc][j] + (BROW ? bias[row] : bias[col]);
        if (OBF) ((unsigned short*)outp)[(size_t)row * ldout + col] = f2bf(v);
        else     ((float*)outp)[(size_t)row * ldout + col] = v;
      }
}

__global__ __launch_bounds__(512, 2) void stage2_k(const unsigned short* __restrict__ Xb,
                                                   const unsigned short* __restrict__ W1b,
                                                   const unsigned short* __restrict__ W2b,
                                                   const float* __restrict__ b1,
                                                   const float* __restrict__ b2,
                                                   unsigned short* __restrict__ fcXT,
                                                   float* __restrict__ fc2,
                                                   const unsigned* __restrict__ hist,
                                                   unsigned* __restrict__ coarse) {
  __shared__ alignas(16) char plds[20480];
  const int bx = blockIdx.x;
  if (bx < 256) {
    // fcXT[o][n] = sum_k W1[o,k]*X[n,k] + b1[o]; bf16 [512][8192]
    int m0 = ((bx >> 3) & 7) * 64;
    int n0 = ((bx & 7) | ((bx >> 6) << 3)) * 256;
    gemm_small_body<true, true>(W1b, Xb, b1, (void*)fcXT, NN, m0, n0, plds, plds + 4096);
  } else if (bx < 512) {
    // fc2[n][o] = sum_k X[n,k]*W2[o,k] + b2[o]; fp32 [8192][512]
    int q = bx - 256;
    gemm_small_body<false, false>(Xb, W2b, b2, (void*)fc2, DD,
                                  (q >> 1) * 64, (q & 1) * 256, plds, plds + 4096);
  } else {
    // coarse: block handles groups {2*(bx-512), 2*(bx-512)+1} via 256-thread halves
    const int tid = threadIdx.x;
    const int half = tid >> 8;                       // 0 or 1
    const int g = ((bx - 512) << 1) | half;
    unsigned v = hist[g * 256 + (tid & 255)];
    for (int off = 32; off > 0; off >>= 1) v += __shfl_down(v, off);
    unsigned* part = (unsigned*)plds;                // 8 wave slots
    if ((tid & 63) == 0) part[tid >> 6] = v;
    __syncthreads();
    if ((tid & 255) == 0)
      coarse[g] = part[half * 4] + part[half * 4 + 1] + part[half * 4 + 2] + part[half * 4 + 3];
  }
}

// ================= median select: coarse scan + owner drill-down =================
__global__ __launch_bounds__(1024) void select_k(const unsigned* __restrict__ hist,
                                                 const unsigned* __restrict__ coarse,
                                                 const unsigned* __restrict__ below,
                                                 unsigned* __restrict__ med) {
  __shared__ unsigned ssum[1024];
  __shared__ int owner;
  __shared__ unsigned tg_s;
  const int t = threadIdx.x;
  unsigned own = coarse[t];
  ssum[t] = own;
  __syncthreads();
  for (int off = 1; off < 1024; off <<= 1) {
    unsigned v = (t >= off) ? ssum[t - off] : 0u;
    __syncthreads();
    ssum[t] += v;
    __syncthreads();
  }
  long long target = K_RANK - (long long)(*below);
  unsigned incl = ssum[t];
  unsigned excl = incl - own;
  if (target >= (long long)excl && target < (long long)incl) {
    owner = t;
    tg_s = (unsigned)(target - (long long)excl);
  }
  __syncthreads();
  const int to = owner;
  const unsigned tg = tg_s;
  unsigned v256 = (t < 256) ? hist[to * 256 + t] : 0u;
  __syncthreads();
  if (t < 256) ssum[t] = v256;
  __syncthreads();
  for (int off = 1; off < 256; off <<= 1) {
    unsigned v = (t < 256 && t >= off) ? ssum[t - off] : 0u;
    __syncthreads();
    if (t < 256) ssum[t] += v;
    __syncthreads();
  }
  if (t < 256) {
    unsigned incl2 = ssum[t];
    unsigned excl2 = incl2 - v256;
    if (tg >= excl2 && tg < incl2) *med = LOB + (unsigned)(to * 256 + t);
  }
}

// ================= main GEMM: 128x512 tile, split-K=4, BK=64, counted-vmcnt ==========
// BK=64 (32 iters) with R6-style gate discipline. Per iter: A(k+1) 4 asm loads FIRST,
// then B(k+1) 8 gl_lds, then 64 MFMA (covers both latencies), then VMCNT(8) = drain
// exactly A(k+1) -> CONV8 x2 -> A[NCUR], then VMCNT(0)+LGKM0+barrier (B(k+1) has had
// the entire MFMA phase to land -> cheap drain; R20's regression came from issuing A
// at the bottom). Asm registers: ONE quad, issued+consumed within the same iter ->
// live set 16 VGPR; total ~212 < 256 cap -> no spill (R19's failure mode avoided).
// LDS = two verbatim R6 sub-tiles per buffer: A dbuf 2x16K + B dbuf 2x64K = 163840B.
static constexpr int LDS_A0 = 0;
static constexpr int LDS_A1 = 16384;
static constexpr int LDS_B0 = 32768;
static constexpr int LDS_B1 = 98304;

__global__ __launch_bounds__(512, 2) void main_gemm_k(const float* __restrict__ A,
                                                      const unsigned short* __restrict__ fcXT,
                                                      const unsigned* __restrict__ medp,
                                                      unsigned short* __restrict__ Up,
                                                      float* __restrict__ Zp) {
  __shared__ alignas(16) char lds[163840];
  const int tid = threadIdx.x, lane = tid & 63, w = tid >> 6;
  const int wm = w >> 2, wn = w & 3;
  const int lr = lane & 15, lq = lane >> 4;
  const int fid = blockIdx.x;
  const int xcd = fid & 7;
  const int ks = xcd >> 1;
  const int m0 = (((xcd & 1) << 5) | (fid >> 3)) << 7;
  const int kbase = ks * 2048;
  const float med = __uint_as_float(*medp);
  const int rB = lane >> 2, kqB = lane & 3;
  const int rA = tid >> 2, cqA = tid & 3;
  const float* aRow = A + (size_t)(m0 + rA) * NN;
  const int ldsAw = rA * 64 + swz(rA, cqA) * 16;

  float zacc = 0.f;
  f32x4 acc[4][8];
#pragma unroll
  for (int i = 0; i < 4; ++i)
#pragma unroll
    for (int j = 0; j < 8; ++j) acc[i][j] = (f32x4){0.f, 0.f, 0.f, 0.f};
  float4 vA0, vA1, vA2, vA3;

#define CONV8(V0, V1, DST)                                                     \
  {                                                                            \
    float vv[8] = {V0.x, V0.y, V0.z, V0.w, V1.x, V1.y, V1.z, V1.w};            \
    short8 pb;                                                                 \
    _Pragma("unroll")                                                          \
    for (int j = 0; j < 8; ++j) {                                              \
      float a_ = vv[j];                                                        \
      float p_ = (a_ < med) ? 1.0f : __expf(a_);                               \
      unsigned short h_ = f2bf(p_);                                            \
      pb[j] = (short)h_;                                                       \
      zacc += bf2f(h_);                                                        \
    }                                                                          \
    *(short8*)(DST) = pb;                                                      \
  }

  // stage 64-col B tile (2 sub-tiles, 8 gl_lds/thread) into buffer at BBASE
#define STAGE_B(KOFF, BBASE)                                                   \
  _Pragma("unroll")                                                            \
  for (int s = 0; s < 2; ++s) {                                                \
    _Pragma("unroll")                                                          \
    for (int i = 0; i < 4; ++i) {                                              \
      int blk = w * 4 + i;                                                     \
      int o = blk * 16 + rB;                                                   \
      gl_lds16(fcXT + ((size_t)o * NN + (KOFF) + s * 32 + swz(o, kqB) * 8),    \
               lds + (BBASE) + s * 32768 + blk * 1024);                        \
    }                                                                          \
  }

  // ---- prologue: B(0)->B0, A(0) C++ loads -> conv -> A0, barrier ----
  STAGE_B(kbase, LDS_B0);
  {
    const float* ap_ = aRow + kbase + cqA * 8;
    float4 t0_ = *(const float4*)ap_;
    float4 t1_ = *(const float4*)(ap_ + 4);
    float4 t2_ = *(const float4*)(ap_ + 32);
    float4 t3_ = *(const float4*)(ap_ + 36);
    CONV8(t0_, t1_, lds + LDS_A0 + ldsAw);
    CONV8(t2_, t3_, lds + LDS_A0 + 8192 + ldsAw);
  }
  __syncthreads();

  // iter kt (32 total): A(kt+1) asm loads FIRST, B(kt+1) gl_lds; 64 MFMA on CUR;
  // VMCNT(8) -> CONV A(kt+1) -> A[NCUR]; VMCNT(0)+LGKM0 -> barrier.
#define ITER(KT, CUR, NCUR)                                                    \
  {                                                                            \
    const int kt_ = (KT);                                                      \
    if (kt_ < 31) {                                                            \
      const float* apf = aRow + kbase + (kt_ + 1) * 64 + cqA * 8;              \
      asm volatile("global_load_dwordx4 %0, %4, off\n\t"                       \
                   "global_load_dwordx4 %1, %4, off offset:16\n\t"             \
                   "global_load_dwordx4 %2, %4, off offset:128\n\t"            \
                   "global_load_dwordx4 %3, %4, off offset:144"                \
                   : "=&v"(vA0), "=&v"(vA1), "=&v"(vA2), "=&v"(vA3)            \
                   : "v"(apf)                                                  \
                   : "memory");                                                \
      STAGE_B(kbase + (kt_ + 1) * 64, LDS_B##NCUR);                            \
    }                                                                          \
    _Pragma("unroll")                                                          \
    for (int ksb = 0; ksb < 2; ++ksb) {                                        \
      short8 af[4], bfr[8];                                                    \
      _Pragma("unroll")                                                        \
      for (int fr = 0; fr < 4; ++fr) {                                         \
        int r = wm * 64 + fr * 16 + lr;                                        \
        af[fr] = *(const short8*)(lds + LDS_A##CUR + ksb * 8192 +              \
                                  r * 64 + swz(r, lq) * 16);                   \
      }                                                                        \
      _Pragma("unroll")                                                        \
      for (int fc = 0; fc < 8; ++fc) {                                         \
        int o = wn * 128 + fc * 16 + lr;                                       \
        bfr[fc] = *(const short8*)(lds + LDS_B##CUR + ksb * 32768 +            \
                                   o * 64 + swz(o, lq) * 16);                  \
      }                                                                        \
      __builtin_amdgcn_s_setprio(1);                                           \
      _Pragma("unroll")                                                        \
      for (int fr = 0; fr < 4; ++fr)                                           \
        _Pragma("unroll")                                                      \
        for (int fc = 0; fc < 8; ++fc)                                         \
          acc[fr][fc] = __builtin_amdgcn_mfma_f32_16x16x32_bf16(               \
              af[fr], bfr[fc], acc[fr][fc], 0, 0, 0);                          \
      __builtin_amdgcn_s_setprio(0);                                           \
    }                                                                          \
    if (kt_ < 31) {                                                            \
      VMCNT(8);                                                                \
      __builtin_amdgcn_sched_barrier(0);                                       \
      CONV8(vA0, vA1, lds + LDS_A##NCUR + ldsAw);                              \
      CONV8(vA2, vA3, lds + LDS_A##NCUR + 8192 + ldsAw);                       \
      VMCNT(0);                                                                \
      LGKM0;                                                                   \
      __builtin_amdgcn_s_barrier();                                            \
    }                                                                          \
  }

#pragma unroll 1
  for (int t2 = 0; t2 < 16; ++t2) {
    ITER(2 * t2,     0, 1);
    ITER(2 * t2 + 1, 1, 0);
  }
#undef ITER
#undef STAGE_B
#undef CONV8

  // ---- epilogue: rowsum reduce (4 threads per row), Up writes ----
  zacc += __shfl_xor(zacc, 1);
  zacc += __shfl_xor(zacc, 2);
  if ((lane & 3) == 0) Zp[(size_t)ks * NN + m0 + rA] = zacc;
#pragma unroll
  for (int fr = 0; fr < 4; ++fr)
#pragma unroll
    for (int fc = 0; fc < 8; ++fc)
#pragma unroll
      for (int j = 0; j < 4; ++j) {
        int row = m0 + wm * 64 + fr * 16 + lq * 4 + j;
        int col = wn * 128 + fc * 16 + lr;
        Up[((size_t)ks << 22) + ((size_t)row << 9) + col] = f2bf(acc[fr][fc][j]);
      }
}

// ================= split-K reduce + epilogue =================
__global__ __launch_bounds__(256) void reduce_k(const unsigned short* __restrict__ Up,
                                                const float* __restrict__ Zp,
                                                const float* __restrict__ fc2,
                                                float* __restrict__ out) {
  long long t = (long long)blockIdx.x * blockDim.x + threadIdx.x;
  if (t >= (long long)NN * DD / 8) return;
  long long base = t << 3;
  int row = (int)(base >> 9);
  float Z = Zp[row] + Zp[NN + row] + Zp[2 * NN + row] + Zp[3 * NN + row];
  float inv = 0.9f / Z;
  float s[8] = {0, 0, 0, 0, 0, 0, 0, 0};
#pragma unroll
  for (int sp = 0; sp < 4; ++sp) {
    const uint4 u = *(const uint4*)(Up + ((long long)sp << 22) + base);
    const unsigned uu[4] = {u.x, u.y, u.z, u.w};
#pragma unroll
    for (int j = 0; j < 4; ++j) {
      s[2 * j]     += __uint_as_float(uu[j] << 16);
      s[2 * j + 1] += __uint_as_float(uu[j] & 0xffff0000u);
    }
  }
  float4 fa = *(const float4*)(fc2 + base);
  float4 fb = *(const float4*)(fc2 + base + 4);
  float fv[8] = {fa.x, fa.y, fa.z, fa.w, fb.x, fb.y, fb.z, fb.w};
  float o[8];
#pragma unroll
  for (int j = 0; j < 8; ++j) {
    float v = 0.1f * fv[j] + inv * s[j];
    o[j] = v >= 0.f ? v : 0.01f * v;
  }
  *(float4*)(out + base)     = (float4){o[0], o[1], o[2], o[3]};
  *(float4*)(out + base + 4) = (float4){o[4], o[5], o[6], o[7]};
}

extern "C" void kernel_launch(void* const* d_in, const int* in_sizes, int n_in,
                              void* d_out, int out_size, void* d_ws, size_t ws_size,
                              hipStream_t stream) {
  const float* A  = (const float*)d_in[0];
  const float* X  = (const float*)d_in[1];
  const float* W1 = (const float*)d_in[2];
  const float* b1 = (const float*)d_in[3];
  const float* W2 = (const float*)d_in[4];
  const float* b2 = (const float*)d_in[5];
  char* ws = (char*)d_ws;
  unsigned* hist   = (unsigned*)(ws + WS_HIST);
  unsigned* cnt    = (unsigned*)(ws + WS_CNT);
  unsigned* med    = (unsigned*)(ws + WS_MED);
  unsigned* coarse = (unsigned*)(ws + WS_COARSE);
  unsigned short* Xb   = (unsigned short*)(ws + WS_XB);
  unsigned short* W1b  = (unsigned short*)(ws + WS_W1B);
  unsigned short* W2b  = (unsigned short*)(ws + WS_W2B);
  unsigned short* fcXT = (unsigned short*)(ws + WS_FCXT);
  float* fc2           = (float*)(ws + WS_FC2);
  unsigned short* Upp  = (unsigned short*)(ws + WS_UP);
  float* Zp            = (float*)(ws + WS_ZP);

  hipLaunchKernelGGL(zero_k, dim3(256), dim3(256), 0, stream, (uint4*)hist, cnt);
  hipLaunchKernelGGL(stage1_k, dim3(1024), dim3(512), 0, stream,
                     A, X, W1, W2, hist, cnt, Xb, W1b, W2b);
  hipLaunchKernelGGL(stage2_k, dim3(1024), dim3(512), 0, stream,
                     Xb, W1b, W2b, b1, b2, fcXT, fc2, hist, coarse);
  hipLaunchKernelGGL(select_k, dim3(1), dim3(1024), 0, stream, hist, coarse, cnt, med);
  hipLaunchKernelGGL(main_gemm_k, dim3(256), dim3(512), 0, stream, A, fcXT, med, Upp, Zp);
  hipLaunchKernelGGL(reduce_k, dim3(2048), dim3(256), 0, stream, Upp, Zp, fc2, (float*)d_out);
}

// Round 22
// 237.154 us; speedup vs baseline: 1.2888x; 1.2523x over previous
//
#include <hip/hip_runtime.h>

#define DEVI __device__ __forceinline__

typedef __attribute__((ext_vector_type(8))) short short8;
typedef __attribute__((ext_vector_type(4))) float f32x4;

static constexpr int NN = 8192;
static constexpr int DD = 512;
static constexpr unsigned LOB = 0x3EFE0000u;  // bits(0.49609375f)
static constexpr unsigned HIB = 0x3F020000u;  // bits(0.5078125f) -> 0x40000 exact-bit bins
static constexpr long long K_RANK = 16775167LL;  // (m-1)/2, m = N(N-1)/2

// ws layout (bytes)
static constexpr size_t WS_HIST   = 0;
static constexpr size_t WS_CNT    = 1048576;
static constexpr size_t WS_MED    = 1048832;
static constexpr size_t WS_COARSE = 1049088;                        // u32 coarse[1024]
static constexpr size_t WS_XB     = 2097152;                        // bf16 X [8192][512]
static constexpr size_t WS_W1B  = WS_XB  + (size_t)NN * DD * 2;     // bf16 W1 [512][512]
static constexpr size_t WS_W2B  = WS_W1B + (size_t)DD * DD * 2;     // bf16 W2 [512][512]
static constexpr size_t WS_FCXT = WS_W2B + (size_t)DD * DD * 2;     // bf16 fcX^T [512][8192]
static constexpr size_t WS_FC2  = WS_FCXT + (size_t)NN * DD * 2;    // f32 fc2X [8192][512]
static constexpr size_t WS_UP   = WS_FC2 + (size_t)NN * DD * 4;     // bf16 U partials [4][8192][512]
static constexpr size_t WS_ZP   = WS_UP  + (size_t)4 * NN * DD * 2; // f32 Z partials [4][8192]

DEVI unsigned short f2bf(float f) {
  unsigned u = __float_as_uint(f);
  u += 0x7fffu + ((u >> 16) & 1u);
  return (unsigned short)(u >> 16);
}
DEVI float bf2f(unsigned short h) { return __uint_as_float(((unsigned)h) << 16); }
DEVI int swz(int row, int kq) { return kq ^ ((row >> 1) & 3); }

DEVI void gl_lds16(const void* g, void* l) {
  __builtin_amdgcn_global_load_lds(
      (const __attribute__((address_space(1))) unsigned*)g,
      (__attribute__((address_space(3))) unsigned*)l, 16, 0, 0);
}

#define VMCNT(n) asm volatile("s_waitcnt vmcnt(" #n ")" ::: "memory")
#define LGKM0 asm volatile("s_waitcnt lgkmcnt(0)" ::: "memory")

// ================= zero_k: scratch init (owned kernel; no hipMemsetAsync) =============
__global__ __launch_bounds__(256) void zero_k(uint4* __restrict__ hist4,
                                              unsigned* __restrict__ cntmed) {
  hist4[blockIdx.x * 256 + threadIdx.x] = (uint4){0u, 0u, 0u, 0u};
  if (blockIdx.x == 0 && threadIdx.x < 2) cntmed[threadIdx.x * 64] = 0u;
}

// ================= stage1: convert (bx<128) || hist (bx>=128, 896 blocks) =============

DEVI void convert_body(const float* __restrict__ X, const float* __restrict__ W1,
                       const float* __restrict__ W2, unsigned short* __restrict__ Xb,
                       unsigned short* __restrict__ W1b, unsigned short* __restrict__ W2b,
                       int cb, int tid) {
  const long long NX = (long long)NN * DD;   // 4194304
  const long long NW = (long long)DD * DD;   // 262144
  const long long total4 = (NX + 2 * NW) / 4;
  for (long long q = (long long)cb * 512 + tid; q < total4; q += 65536LL) {
    long long e = q << 2;
    const float4* src; unsigned short* dst; long long off;
    if (e < NX)           { src = (const float4*)X;  dst = Xb;  off = e; }
    else if (e < NX + NW) { src = (const float4*)W1; dst = W1b; off = e - NX; }
    else                  { src = (const float4*)W2; dst = W2b; off = e - NX - NW; }
    float4 v = src[off >> 2];
    ushort4 o;
    o.x = f2bf(v.x); o.y = f2bf(v.y); o.z = f2bf(v.z); o.w = f2bf(v.w);
    *(ushort4*)(dst + off) = o;
  }
}

// hist: 8-deep memory-level parallelism (R13/R14-proven body).
DEVI void hist_body(const float* __restrict__ A, unsigned* __restrict__ hist,
                    unsigned* __restrict__ below, int hb, int tid) {
  unsigned cnt = 0;
  const float4* A4 = (const float4*)A;
  const long long STR = 458752LL;  // 896 blocks * 512 threads
#pragma unroll 1
  for (long long q0 = (long long)hb * 512 + tid; q0 < 16777216LL; q0 += 8 * STR) {
    float4 v[8];
    int act = 0;
#pragma unroll
    for (int i = 0; i < 8; ++i) {  // issue up to 8 independent loads
      long long qi = q0 + i * STR;
      if (qi < 16777216LL) {
        int row = (int)(qi >> 11);
        int col = (int)((qi & 2047) << 2);
        if (col + 3 > row) { act |= 1 << i; v[i] = A4[qi]; }
      }
    }
#pragma unroll
    for (int i = 0; i < 8; ++i) {
      if (act & (1 << i)) {
        long long qi = q0 + i * STR;
        int row = (int)(qi >> 11);
        int col = (int)((qi & 2047) << 2);
        float vv[4] = {v[i].x, v[i].y, v[i].z, v[i].w};
#pragma unroll
        for (int j = 0; j < 4; ++j) {
          if (col + j > row) {
            unsigned u = __float_as_uint(vv[j]);
            if (u < LOB) cnt++;
            else if (u < HIB) atomicAdd(&hist[u - LOB], 1u);
          }
        }
      }
    }
  }
  for (int off = 32; off > 0; off >>= 1) cnt += __shfl_down(cnt, off);
  if ((tid & 63) == 0 && cnt) atomicAdd(below, cnt);
}

__global__ __launch_bounds__(512) void stage1_k(const float* __restrict__ A,
                                                const float* __restrict__ X,
                                                const float* __restrict__ W1,
                                                const float* __restrict__ W2,
                                                unsigned* __restrict__ hist,
                                                unsigned* __restrict__ below,
                                                unsigned short* __restrict__ Xb,
                                                unsigned short* __restrict__ W1b,
                                                unsigned short* __restrict__ W2b) {
  const int bx = blockIdx.x;
  if (bx < 128) convert_body(X, W1, W2, Xb, W1b, W2b, bx, threadIdx.x);
  else          hist_body(A, hist, below, bx - 128, threadIdx.x);
}

// ===== stage2: gemm1 (bx<256) || gemm2 (<512) || coarse hist sums (512..1023) =========

// NT-GEMM (bf16 MFMA): out[m,n] = sum_k Am[m,k]*Bm[n,k] + bias. 64x256 tile, BK=32.
template <bool BROW, bool OBF>
DEVI void gemm_small_body(const unsigned short* __restrict__ Am,
                          const unsigned short* __restrict__ Bm,
                          const float* __restrict__ bias, void* __restrict__ outp,
                          int ldout, int m0, int n0, char* apB, char* btB) {
  const int tid = threadIdx.x, lane = tid & 63, w = tid >> 6;
  const int wm = w >> 2, wn = w & 3;
  const int lr = lane & 15, lq = lane >> 4;
  const int rL = lane >> 2, kq = lane & 3;
  f32x4 acc[2][4];
#pragma unroll
  for (int i = 0; i < 2; ++i)
#pragma unroll
    for (int j = 0; j < 4; ++j) acc[i][j] = (f32x4){0.f, 0.f, 0.f, 0.f};

#pragma unroll 1
  for (int kt = 0; kt < 16; ++kt) {
    const int k0 = kt * 32;
    __syncthreads();
    if (w < 4) {
      int r = w * 16 + rL;
      gl_lds16(Am + ((size_t)(m0 + r) * DD + k0 + swz(r, kq) * 8), apB + w * 1024);
    }
#pragma unroll
    for (int i = 0; i < 2; ++i) {
      int blk = w * 2 + i;
      int r = blk * 16 + rL;
      gl_lds16(Bm + ((size_t)(n0 + r) * DD + k0 + swz(r, kq) * 8), btB + blk * 1024);
    }
    __syncthreads();
    short8 a[2], b[4];
#pragma unroll
    for (int fr = 0; fr < 2; ++fr) {
      int r = wm * 32 + fr * 16 + lr;
      a[fr] = *(const short8*)(apB + r * 64 + swz(r, lq) * 16);
    }
#pragma unroll
    for (int fc = 0; fc < 4; ++fc) {
      int r = wn * 64 + fc * 16 + lr;
      b[fc] = *(const short8*)(btB + r * 64 + swz(r, lq) * 16);
    }
#pragma unroll
    for (int fr = 0; fr < 2; ++fr)
#pragma unroll
      for (int fc = 0; fc < 4; ++fc)
        acc[fr][fc] = __builtin_amdgcn_mfma_f32_16x16x32_bf16(a[fr], b[fc], acc[fr][fc], 0, 0, 0);
  }
#pragma unroll
  for (int fr = 0; fr < 2; ++fr)
#pragma unroll
    for (int fc = 0; fc < 4; ++fc)
#pragma unroll
      for (int j = 0; j < 4; ++j) {
        int row = m0 + wm * 32 + fr * 16 + lq * 4 + j;
        int col = n0 + wn * 64 + fc * 16 + lr;
        float v = acc[fr][fc][j] + (BROW ? bias[row] : bias[col]);
        if (OBF) ((unsigned short*)outp)[(size_t)row * ldout + col] = f2bf(v);
        else     ((float*)outp)[(size_t)row * ldout + col] = v;
      }
}

__global__ __launch_bounds__(512, 2) void stage2_k(const unsigned short* __restrict__ Xb,
                                                   const unsigned short* __restrict__ W1b,
                                                   const unsigned short* __restrict__ W2b,
                                                   const float* __restrict__ b1,
                                                   const float* __restrict__ b2,
                                                   unsigned short* __restrict__ fcXT,
                                                   float* __restrict__ fc2,
                                                   const unsigned* __restrict__ hist,
                                                   unsigned* __restrict__ coarse) {
  __shared__ alignas(16) char plds[20480];
  const int bx = blockIdx.x;
  if (bx < 256) {
    // fcXT[o][n] = sum_k W1[o,k]*X[n,k] + b1[o]; bf16 [512][8192]
    int m0 = ((bx >> 3) & 7) * 64;
    int n0 = ((bx & 7) | ((bx >> 6) << 3)) * 256;
    gemm_small_body<true, true>(W1b, Xb, b1, (void*)fcXT, NN, m0, n0, plds, plds + 4096);
  } else if (bx < 512) {
    // fc2[n][o] = sum_k X[n,k]*W2[o,k] + b2[o]; fp32 [8192][512]
    int q = bx - 256;
    gemm_small_body<false, false>(Xb, W2b, b2, (void*)fc2, DD,
                                  (q >> 1) * 64, (q & 1) * 256, plds, plds + 4096);
  } else {
    // coarse: block handles groups {2*(bx-512), 2*(bx-512)+1} via 256-thread halves
    const int tid = threadIdx.x;
    const int half = tid >> 8;                       // 0 or 1
    const int g = ((bx - 512) << 1) | half;
    unsigned v = hist[g * 256 + (tid & 255)];
    for (int off = 32; off > 0; off >>= 1) v += __shfl_down(v, off);
    unsigned* part = (unsigned*)plds;                // 8 wave slots
    if ((tid & 63) == 0) part[tid >> 6] = v;
    __syncthreads();
    if ((tid & 255) == 0)
      coarse[g] = part[half * 4] + part[half * 4 + 1] + part[half * 4 + 2] + part[half * 4 + 3];
  }
}

// ================= median select: coarse scan + owner drill-down =================
__global__ __launch_bounds__(1024) void select_k(const unsigned* __restrict__ hist,
                                                 const unsigned* __restrict__ coarse,
                                                 const unsigned* __restrict__ below,
                                                 unsigned* __restrict__ med) {
  __shared__ unsigned ssum[1024];
  __shared__ int owner;
  __shared__ unsigned tg_s;
  const int t = threadIdx.x;
  unsigned own = coarse[t];
  ssum[t] = own;
  __syncthreads();
  for (int off = 1; off < 1024; off <<= 1) {
    unsigned v = (t >= off) ? ssum[t - off] : 0u;
    __syncthreads();
    ssum[t] += v;
    __syncthreads();
  }
  long long target = K_RANK - (long long)(*below);
  unsigned incl = ssum[t];
  unsigned excl = incl - own;
  if (target >= (long long)excl && target < (long long)incl) {
    owner = t;
    tg_s = (unsigned)(target - (long long)excl);
  }
  __syncthreads();
  const int to = owner;
  const unsigned tg = tg_s;
  unsigned v256 = (t < 256) ? hist[to * 256 + t] : 0u;
  __syncthreads();
  if (t < 256) ssum[t] = v256;
  __syncthreads();
  for (int off = 1; off < 256; off <<= 1) {
    unsigned v = (t < 256 && t >= off) ? ssum[t - off] : 0u;
    __syncthreads();
    if (t < 256) ssum[t] += v;
    __syncthreads();
  }
  if (t < 256) {
    unsigned incl2 = ssum[t];
    unsigned excl2 = incl2 - v256;
    if (tg >= excl2 && tg < incl2) *med = LOB + (unsigned)(to * 256 + t);
  }
}

// ================= main GEMM: 128x512 tile, split-K=4, counted-vmcnt pipeline =========
// R6-proven body (best measured). flat grid 256; xcd = fid&7 hosts ks = xcd>>1.
// 8 waves (2x4) of 64x128. LDS: A dbuf 2x8KB + B dbuf 2x32KB = 80KB.
static constexpr int LDS_A0 = 0;
static constexpr int LDS_A1 = 8192;
static constexpr int LDS_B0 = 16384;
static constexpr int LDS_B1 = 49152;

__global__ __launch_bounds__(512, 2) void main_gemm_k(const float* __restrict__ A,
                                                      const unsigned short* __restrict__ fcXT,
                                                      const unsigned* __restrict__ medp,
                                                      unsigned short* __restrict__ Up,
                                                      float* __restrict__ Zp) {
  __shared__ alignas(16) char lds[81920];
  const int tid = threadIdx.x, lane = tid & 63, w = tid >> 6;
  const int wm = w >> 2, wn = w & 3;
  const int lr = lane & 15, lq = lane >> 4;
  const int fid = blockIdx.x;
  const int xcd = fid & 7;
  const int ks = xcd >> 1;
  const int m0 = (((xcd & 1) << 5) | (fid >> 3)) << 7;
  const int kbase = ks * 2048;
  const float med = __uint_as_float(*medp);
  const int rB = lane >> 2, kqB = lane & 3;
  const int rA = tid >> 2, cqA = tid & 3;
  const float* aRow = A + (size_t)(m0 + rA) * NN;
  const int ldsAw = rA * 64 + swz(rA, cqA) * 16;

  float zacc = 0.f;
  f32x4 acc[4][8];
#pragma unroll
  for (int i = 0; i < 4; ++i)
#pragma unroll
    for (int j = 0; j < 8; ++j) acc[i][j] = (f32x4){0.f, 0.f, 0.f, 0.f};
  float4 vA00, vA01, vA10, vA11;

#define CONV8(V0, V1, DST)                                                     \
  {                                                                            \
    float vv[8] = {V0.x, V0.y, V0.z, V0.w, V1.x, V1.y, V1.z, V1.w};            \
    short8 pb;                                                                 \
    _Pragma("unroll")                                                          \
    for (int j = 0; j < 8; ++j) {                                              \
      float a_ = vv[j];                                                        \
      float p_ = (a_ < med) ? 1.0f : __expf(a_);                               \
      unsigned short h_ = f2bf(p_);                                            \
      pb[j] = (short)h_;                                                       \
      zacc += bf2f(h_);                                                        \
    }                                                                          \
    *(short8*)(DST) = pb;                                                      \
  }

  // ---- prologue: B(0)->bufB0, A(0) C++ loads -> convert -> bufA0, A(1) -> vA0* ----
  {
#pragma unroll
    for (int i = 0; i < 4; ++i) {
      int blk = w * 4 + i;
      int o = blk * 16 + rB;
      gl_lds16(fcXT + ((size_t)o * NN + kbase + swz(o, kqB) * 8), lds + LDS_B0 + blk * 1024);
    }
    const float* ap0 = aRow + kbase + cqA * 8;
    float4 t0 = *(const float4*)ap0;
    float4 t1 = *(const float4*)(ap0 + 4);
    vA00 = *(const float4*)(ap0 + 32);
    vA01 = *(const float4*)(ap0 + 36);
    CONV8(t0, t1, lds + LDS_A0 + ldsAw);
  }
  __syncthreads();

  // per iter kt: issue B(kt+1)->bufB[NCUR] (4 vm), A(kt+2)->vA[NCUR] (2 vm asm);
  // ds_read frags bufs[CUR], MFMA x32; vmcnt(6)->conv A(kt+1)->ds_write bufA[NCUR];
  // vmcnt(2)+lgkm0 -> s_barrier. (A(kt+2) stays in flight across barrier)
#define ITER(KT, CUR, NCUR, VAC0, VAC1, VAN0, VAN1)                            \
  {                                                                            \
    const int kt_ = (KT);                                                      \
    if (kt_ < 63) {                                                            \
      const int k1 = kbase + (kt_ + 1) * 32;                                   \
      _Pragma("unroll")                                                        \
      for (int i = 0; i < 4; ++i) {                                            \
        int blk = w * 4 + i;                                                   \
        int o = blk * 16 + rB;                                                 \
        gl_lds16(fcXT + ((size_t)o * NN + k1 + swz(o, kqB) * 8),               \
                 lds + LDS_B##NCUR + blk * 1024);                              \
      }                                                                        \
      if (kt_ < 62) {                                                          \
        const float* apf = aRow + kbase + (kt_ + 2) * 32 + cqA * 8;            \
        asm volatile("global_load_dwordx4 %0, %2, off\n\t"                     \
                     "global_load_dwordx4 %1, %2, off offset:16"               \
                     : "=&v"(VAN0), "=&v"(VAN1)                                \
                     : "v"(apf)                                                \
                     : "memory");                                              \
      }                                                                        \
    }                                                                          \
    short8 af[4], bfr[8];                                                      \
    _Pragma("unroll")                                                          \
    for (int fr = 0; fr < 4; ++fr) {                                           \
      int r = wm * 64 + fr * 16 + lr;                                          \
      af[fr] = *(const short8*)(lds + LDS_A##CUR + r * 64 + swz(r, lq) * 16);  \
    }                                                                          \
    _Pragma("unroll")                                                          \
    for (int fc = 0; fc < 8; ++fc) {                                           \
      int o = wn * 128 + fc * 16 + lr;                                         \
      bfr[fc] = *(const short8*)(lds + LDS_B##CUR + o * 64 + swz(o, lq) * 16); \
    }                                                                          \
    __builtin_amdgcn_s_setprio(1);                                             \
    _Pragma("unroll")                                                          \
    for (int fr = 0; fr < 4; ++fr)                                             \
      _Pragma("unroll")                                                        \
      for (int fc = 0; fc < 8; ++fc)                                           \
        acc[fr][fc] = __builtin_amdgcn_mfma_f32_16x16x32_bf16(af[fr], bfr[fc], \
                                                              acc[fr][fc], 0, 0, 0); \
    __builtin_amdgcn_s_setprio(0);                                             \
    if (kt_ < 63) {                                                            \
      if (kt_ < 62) { VMCNT(6); } else { VMCNT(4); }                           \
      __builtin_amdgcn_sched_barrier(0);                                       \
      CONV8(VAC0, VAC1, lds + LDS_A##NCUR + ldsAw);                            \
      if (kt_ < 62) { VMCNT(2); } else { VMCNT(0); }                           \
      LGKM0;                                                                   \
      __builtin_amdgcn_s_barrier();                                            \
    }                                                                          \
  }

#pragma unroll 1
  for (int t2 = 0; t2 < 32; ++t2) {
    ITER(2 * t2,     0, 1, vA00, vA01, vA10, vA11);
    ITER(2 * t2 + 1, 1, 0, vA10, vA11, vA00, vA01);
  }
#undef ITER
#undef CONV8

  // ---- epilogue: rowsum reduce (4 threads per row), Up writes ----
  zacc += __shfl_xor(zacc, 1);
  zacc += __shfl_xor(zacc, 2);
  if ((lane & 3) == 0) Zp[(size_t)ks * NN + m0 + rA] = zacc;
#pragma unroll
  for (int fr = 0; fr < 4; ++fr)
#pragma unroll
    for (int fc = 0; fc < 8; ++fc)
#pragma unroll
      for (int j = 0; j < 4; ++j) {
        int row = m0 + wm * 64 + fr * 16 + lq * 4 + j;
        int col = wn * 128 + fc * 16 + lr;
        Up[((size_t)ks << 22) + ((size_t)row << 9) + col] = f2bf(acc[fr][fc][j]);
      }
}

// ================= split-K reduce + epilogue =================
__global__ __launch_bounds__(256) void reduce_k(const unsigned short* __restrict__ Up,
                                                const float* __restrict__ Zp,
                                                const float* __restrict__ fc2,
                                                float* __restrict__ out) {
  long long t = (long long)blockIdx.x * blockDim.x + threadIdx.x;
  if (t >= (long long)NN * DD / 8) return;
  long long base = t << 3;
  int row = (int)(base >> 9);
  float Z = Zp[row] + Zp[NN + row] + Zp[2 * NN + row] + Zp[3 * NN + row];
  float inv = 0.9f / Z;
  float s[8] = {0, 0, 0, 0, 0, 0, 0, 0};
#pragma unroll
  for (int sp = 0; sp < 4; ++sp) {
    const uint4 u = *(const uint4*)(Up + ((long long)sp << 22) + base);
    const unsigned uu[4] = {u.x, u.y, u.z, u.w};
#pragma unroll
    for (int j = 0; j < 4; ++j) {
      s[2 * j]     += __uint_as_float(uu[j] << 16);
      s[2 * j + 1] += __uint_as_float(uu[j] & 0xffff0000u);
    }
  }
  float4 fa = *(const float4*)(fc2 + base);
  float4 fb = *(const float4*)(fc2 + base + 4);
  float fv[8] = {fa.x, fa.y, fa.z, fa.w, fb.x, fb.y, fb.z, fb.w};
  float o[8];
#pragma unroll
  for (int j = 0; j < 8; ++j) {
    float v = 0.1f * fv[j] + inv * s[j];
    o[j] = v >= 0.f ? v : 0.01f * v;
  }
  *(float4*)(out + base)     = (float4){o[0], o[1], o[2], o[3]};
  *(float4*)(out + base + 4) = (float4){o[4], o[5], o[6], o[7]};
}

extern "C" void kernel_launch(void* const* d_in, const int* in_sizes, int n_in,
                              void* d_out, int out_size, void* d_ws, size_t ws_size,
                              hipStream_t stream) {
  const float* A  = (const float*)d_in[0];
  const float* X  = (const float*)d_in[1];
  const float* W1 = (const float*)d_in[2];
  const float* b1 = (const float*)d_in[3];
  const float* W2 = (const float*)d_in[4];
  const float* b2 = (const float*)d_in[5];
  char* ws = (char*)d_ws;
  unsigned* hist   = (unsigned*)(ws + WS_HIST);
  unsigned* cnt    = (unsigned*)(ws + WS_CNT);
  unsigned* med    = (unsigned*)(ws + WS_MED);
  unsigned* coarse = (unsigned*)(ws + WS_COARSE);
  unsigned short* Xb   = (unsigned short*)(ws + WS_XB);
  unsigned short* W1b  = (unsigned short*)(ws + WS_W1B);
  unsigned short* W2b  = (unsigned short*)(ws + WS_W2B);
  unsigned short* fcXT = (unsigned short*)(ws + WS_FCXT);
  float* fc2           = (float*)(ws + WS_FC2);
  unsigned short* Upp  = (unsigned short*)(ws + WS_UP);
  float* Zp            = (float*)(ws + WS_ZP);

  hipLaunchKernelGGL(zero_k, dim3(256), dim3(256), 0, stream, (uint4*)hist, cnt);
  hipLaunchKernelGGL(stage1_k, dim3(1024), dim3(512), 0, stream,
                     A, X, W1, W2, hist, cnt, Xb, W1b, W2b);
  hipLaunchKernelGGL(stage2_k, dim3(1024), dim3(512), 0, stream,
                     Xb, W1b, W2b, b1, b2, fcXT, fc2, hist, coarse);
  hipLaunchKernelGGL(select_k, dim3(1), dim3(1024), 0, stream, hist, coarse, cnt, med);
  hipLaunchKernelGGL(main_gemm_k, dim3(256), dim3(512), 0, stream, A, fcXT, med, Upp, Zp);
  hipLaunchKernelGGL(reduce_k, dim3(2048), dim3(256), 0, stream, Upp, Zp, fc2, (float*)d_out);
}